// Round 1
// baseline (850.119 us; speedup 1.0000x reference)
//
#include <hip/hip_runtime.h>
#include <hip/hip_bf16.h>
#include <stdint.h>

// LocalEnhancementModule on MI355X (gfx950).
// B=16 C=16 H=W=256 NP=16 -> P=256, D=4096, E=512, M=B*P=4096.
// Design:
//  prep_p: x -> p_hi/p_lo bf16 [M,D] (hi/lo split for accurate theta/f GEMM)
//  prep_w: [theta_w|f_w] fp32 [D,1024] -> transposed bf16 hi/lo [1024,D]
//  prep_g: g_w fp32 [D,D] -> transposed bf16 [D(n),D(k)]
//  gemm1 : 3-pass split bf16 MFMA -> theta/f fp32 [M,1024] (+bias)
//  scores: fp32 scores theta@f^T per batch + softmax -> weights [B,P,P]
//  gemm2 : bf16 MFMA p_hi @ g_w, epilogue out = scale*w*(acc+g_b) + x

typedef __hip_bfloat16 bf16;
typedef __bf16 bf16x8 __attribute__((ext_vector_type(8)));
typedef float f32x4 __attribute__((ext_vector_type(4)));

#define GLOBAL_AS __attribute__((address_space(1)))
#define LDS_AS __attribute__((address_space(3)))

__device__ __forceinline__ void gload_lds16(const void* g, void* l) {
    // async global->LDS, 16B per lane; LDS dest = wave-uniform base + lane*16
    void* gg = const_cast<void*>(g);
    __builtin_amdgcn_global_load_lds((GLOBAL_AS void*)gg, (LDS_AS void*)l, 16, 0, 0);
}

// ---------------- prep kernels ----------------

__global__ __launch_bounds__(256) void prep_p(const float* __restrict__ x,
                                              bf16* __restrict__ pHi,
                                              bf16* __restrict__ pLo) {
    int tid = blockIdx.x * 256 + threadIdx.x;        // over [B][C][H][W/4]
    int w4 = tid & 63;
    int h  = (tid >> 6) & 255;
    int c  = (tid >> 14) & 15;
    int b  = tid >> 18;
    float4 v = ((const float4*)x)[tid];
    int i = h >> 4, y = h & 15, j = w4 >> 2, zb = (w4 & 3) * 4;
    int m = b * 256 + i * 16 + j;
    int k = c * 256 + y * 16 + zb;
    size_t o = (size_t)m * 4096 + k;
    float vs[4] = {v.x, v.y, v.z, v.w};
#pragma unroll
    for (int q = 0; q < 4; ++q) {
        bf16 hv = __float2bfloat16(vs[q]);
        float rem = vs[q] - __bfloat162float(hv);
        pHi[o + q] = hv;
        pLo[o + q] = __float2bfloat16(rem);
    }
}

__global__ __launch_bounds__(256) void prep_w(const float* __restrict__ theta_w,
                                              const float* __restrict__ f_w,
                                              bf16* __restrict__ wHi,
                                              bf16* __restrict__ wLo) {
    __shared__ float tile[32][33];
    int t = threadIdx.x;
    int tx = t & 31, ty = t >> 5;            // ty 0..7
    int k0 = blockIdx.x * 32;                // 0..4064
    int e0 = blockIdx.y * 32;                // 0..992
#pragma unroll
    for (int r = 0; r < 4; ++r) {
        int k = k0 + ty + r * 8;
        int e = e0 + tx;
        float v = (e < 512) ? theta_w[(size_t)k * 512 + e]
                            : f_w[(size_t)k * 512 + (e - 512)];
        tile[ty + r * 8][tx] = v;
    }
    __syncthreads();
#pragma unroll
    for (int r = 0; r < 4; ++r) {
        int e = e0 + ty + r * 8;
        int k = k0 + tx;
        float v = tile[tx][ty + r * 8];
        bf16 hv = __float2bfloat16(v);
        float rem = v - __bfloat162float(hv);
        wHi[(size_t)e * 4096 + k] = hv;
        wLo[(size_t)e * 4096 + k] = __float2bfloat16(rem);
    }
}

__global__ __launch_bounds__(256) void prep_g(const float* __restrict__ g_w,
                                              bf16* __restrict__ gwt) {
    __shared__ float tile[32][33];
    int t = threadIdx.x;
    int tx = t & 31, ty = t >> 5;
    int k0 = blockIdx.x * 32;
    int n0 = blockIdx.y * 32;
#pragma unroll
    for (int r = 0; r < 4; ++r) {
        int k = k0 + ty + r * 8;
        tile[ty + r * 8][tx] = g_w[(size_t)k * 4096 + (n0 + tx)];
    }
    __syncthreads();
#pragma unroll
    for (int r = 0; r < 4; ++r) {
        int n = n0 + ty + r * 8;
        int k = k0 + tx;
        gwt[(size_t)n * 4096 + k] = __float2bfloat16(tile[tx][ty + r * 8]);
    }
}

// ---------------- shared GEMM core ----------------
// BM=BN=128, BK=32, 256 threads (4 waves, 2x2 wave grid, 64x64/wave).
// A: [M,K] bf16 row-major; Bt: [N,K] bf16 row-major (B transposed).
__device__ __forceinline__ void gemm_pass(const bf16* A, const bf16* Bt, int K,
                                          int m0, int n0, bf16* As, bf16* Bs,
                                          f32x4 (&acc)[4][4]) {
    int t = threadIdx.x, lane = t & 63, wave = t >> 6;
    int wm = wave & 1, wn = wave >> 1;
    int lr = lane & 15, lq = lane >> 4;
    const bf16* gA = A + (size_t)m0 * K;
    const bf16* gB = Bt + (size_t)n0 * K;
    int chunk0 = wave * 2;
    int srow0 = lane >> 2;
    int cb = (lane & 3) * 16;   // byte offset within a 64B row
    for (int kt = 0; kt < K; kt += 32) {
        // stage A/B tiles (128 x 32 bf16 = 8KB each): 8 chunks of 16 rows
#pragma unroll
        for (int tt = 0; tt < 2; ++tt) {
            int chunk = chunk0 + tt;
            int row = chunk * 16 + srow0;
            gload_lds16((const char*)(gA + ((size_t)row * K + kt)) + cb,
                        (char*)As + chunk * 1024);
            gload_lds16((const char*)(gB + ((size_t)row * K + kt)) + cb,
                        (char*)Bs + chunk * 1024);
        }
        __syncthreads();
        bf16x8 af[4], bfr[4];
#pragma unroll
        for (int mt = 0; mt < 4; ++mt)
            af[mt] = *(const bf16x8*)((const char*)As + (wm * 64 + mt * 16 + lr) * 64 + lq * 16);
#pragma unroll
        for (int nt = 0; nt < 4; ++nt)
            bfr[nt] = *(const bf16x8*)((const char*)Bs + (wn * 64 + nt * 16 + lr) * 64 + lq * 16);
#pragma unroll
        for (int mt = 0; mt < 4; ++mt)
#pragma unroll
            for (int nt = 0; nt < 4; ++nt)
                acc[mt][nt] = __builtin_amdgcn_mfma_f32_16x16x32_bf16(
                    af[mt], bfr[nt], acc[mt][nt], 0, 0, 0);
        __syncthreads();
    }
}

// ---------------- gemm1: theta/f with hi/lo split ----------------

__global__ __launch_bounds__(256) void gemm1(const bf16* __restrict__ pHi,
                                             const bf16* __restrict__ pLo,
                                             const bf16* __restrict__ wHi,
                                             const bf16* __restrict__ wLo,
                                             const float* __restrict__ theta_b,
                                             const float* __restrict__ f_b,
                                             float* __restrict__ C1) {
    __shared__ bf16 As[128 * 32];
    __shared__ bf16 Bs[128 * 32];
    int m0 = blockIdx.x * 128, n0 = blockIdx.y * 128;
    f32x4 acc[4][4] = {};
    gemm_pass(pLo, wHi, 4096, m0, n0, As, Bs, acc);   // lo*hi
    gemm_pass(pHi, wLo, 4096, m0, n0, As, Bs, acc);   // hi*lo
    gemm_pass(pHi, wHi, 4096, m0, n0, As, Bs, acc);   // hi*hi
    int t = threadIdx.x, lane = t & 63, wave = t >> 6;
    int wm = wave & 1, wn = wave >> 1;
    int lr = lane & 15, lq = lane >> 4;
#pragma unroll
    for (int mt = 0; mt < 4; ++mt)
#pragma unroll
        for (int nt = 0; nt < 4; ++nt) {
            int col = n0 + wn * 64 + nt * 16 + lr;
            float bias = (col < 512) ? theta_b[col] : f_b[col - 512];
#pragma unroll
            for (int reg = 0; reg < 4; ++reg) {
                int row = m0 + wm * 64 + mt * 16 + lq * 4 + reg;
                C1[(size_t)row * 1024 + col] = acc[mt][nt][reg] + bias;
            }
        }
}

// ---------------- scores + softmax ----------------
// block: (pi_tile=16 rows of one batch); theta rows staged in LDS; f read from L2.

__global__ __launch_bounds__(256) void scores_softmax(const float* __restrict__ C1,
                                                      float* __restrict__ wts) {
    __shared__ float th[16 * 512];
    __shared__ float sc[16 * 256];
    int t = threadIdx.x;
    int pi0 = blockIdx.x * 16;
    int b = blockIdx.y;
#pragma unroll
    for (int it = 0; it < 8; ++it) {
        int idx = it * 256 + t;      // float4 id 0..2047
        int row = idx >> 7;          // 0..15
        int c4 = idx & 127;
        float4 v = *(const float4*)(C1 + ((size_t)(b * 256 + pi0 + row)) * 1024 + c4 * 4);
        *(float4*)(th + row * 512 + c4 * 4) = v;
    }
    __syncthreads();
    int pil = t >> 4;
    int pj0 = (t & 15) * 16;
    for (int pj = pj0; pj < pj0 + 16; ++pj) {
        const float4* fp = (const float4*)(C1 + ((size_t)(b * 256 + pj)) * 1024 + 512);
        const float4* tp = (const float4*)(th + pil * 512);
        float a0 = 0.f, a1 = 0.f, a2 = 0.f, a3 = 0.f;
        for (int e = 0; e < 128; ++e) {
            float4 fa = fp[e], ta = tp[e];
            a0 += ta.x * fa.x; a1 += ta.y * fa.y;
            a2 += ta.z * fa.z; a3 += ta.w * fa.w;
        }
        sc[pil * 256 + pj] = (a0 + a1) + (a2 + a3);
    }
    __syncthreads();
    int lane = t & 63, wv = t >> 6;
    for (int r = wv * 4; r < wv * 4 + 4; ++r) {
        float v0 = sc[r * 256 + lane];
        float v1 = sc[r * 256 + 64 + lane];
        float v2 = sc[r * 256 + 128 + lane];
        float v3 = sc[r * 256 + 192 + lane];
        float mx = fmaxf(fmaxf(v0, v1), fmaxf(v2, v3));
#pragma unroll
        for (int s = 32; s >= 1; s >>= 1) mx = fmaxf(mx, __shfl_xor(mx, s, 64));
        float e0 = expf(v0 - mx), e1 = expf(v1 - mx);
        float e2 = expf(v2 - mx), e3 = expf(v3 - mx);
        float sm = (e0 + e1) + (e2 + e3);
#pragma unroll
        for (int s = 32; s >= 1; s >>= 1) sm += __shfl_xor(sm, s, 64);
        float inv = 1.0f / sm;
        size_t base = ((size_t)(b * 256 + pi0 + r)) * 256;
        wts[base + lane] = e0 * inv;
        wts[base + 64 + lane] = e1 * inv;
        wts[base + 128 + lane] = e2 * inv;
        wts[base + 192 + lane] = e3 * inv;
    }
}

// ---------------- gemm2: g GEMM + fused gating epilogue ----------------

__global__ __launch_bounds__(256) void gemm2(const bf16* __restrict__ pHi,
                                             const bf16* __restrict__ gwt,
                                             const float* __restrict__ g_b,
                                             const float* __restrict__ wts,
                                             const float* __restrict__ x,
                                             const float* __restrict__ scale,
                                             float* __restrict__ out) {
    __shared__ bf16 As[128 * 32];
    __shared__ bf16 Bs[128 * 32];
    int m0 = blockIdx.x * 128, n0 = blockIdx.y * 128;
    f32x4 acc[4][4] = {};
    gemm_pass(pHi, gwt, 4096, m0, n0, As, Bs, acc);
    int t = threadIdx.x, lane = t & 63, wave = t >> 6;
    int wm = wave & 1, wn = wave >> 1;
    int lr = lane & 15, lq = lane >> 4;
    float scl = scale[0];
#pragma unroll
    for (int mt = 0; mt < 4; ++mt)
#pragma unroll
        for (int nt = 0; nt < 4; ++nt) {
            int ng = n0 + wn * 64 + nt * 16 + lr;   // d_out = cc*256 + nidx
            float gb = g_b[ng];
            int cc = ng >> 8, nidx = ng & 255;
            int y = nidx >> 4, z = nidx & 15;
#pragma unroll
            for (int reg = 0; reg < 4; ++reg) {
                int mg = m0 + wm * 64 + mt * 16 + lq * 4 + reg;  // b*256 + pi
                int bb = mg >> 8, pi = mg & 255;
                int i = pi >> 4, j = pi & 15;
                float wt = wts[(size_t)mg * 256 + nidx];
                float gval = acc[mt][nt][reg] + gb;
                size_t idx = ((((size_t)(bb * 16 + cc)) * 256) + i * 16 + y) * 256
                             + (j * 16 + z);
                out[idx] = scl * wt * gval + x[idx];
            }
        }
}

// ---------------- launch ----------------

extern "C" void kernel_launch(void* const* d_in, const int* in_sizes, int n_in,
                              void* d_out, int out_size, void* d_ws, size_t ws_size,
                              hipStream_t stream) {
    const float* x       = (const float*)d_in[0];
    const float* theta_w = (const float*)d_in[1];
    const float* theta_b = (const float*)d_in[2];
    const float* f_w     = (const float*)d_in[3];
    const float* f_b     = (const float*)d_in[4];
    const float* g_w     = (const float*)d_in[5];
    const float* g_b     = (const float*)d_in[6];
    const float* scale   = (const float*)d_in[7];
    (void)in_sizes; (void)n_in; (void)out_size; (void)ws_size;

    char* ws = (char*)d_ws;
    bf16*  pHi = (bf16*)(ws);                              // 32 MiB
    bf16*  pLo = (bf16*)(ws + (size_t)33554432);           // 32 MiB
    bf16*  wHi = (bf16*)(ws + (size_t)67108864);           // 8 MiB
    bf16*  wLo = (bf16*)(ws + (size_t)75497472);           // 8 MiB
    bf16*  gwt = (bf16*)(ws + (size_t)83886080);           // 32 MiB
    float* C1  = (float*)(ws + (size_t)117440512);         // 16 MiB (theta|f)
    float* wts = (float*)(ws + (size_t)134217728);         // 4 MiB

    prep_p<<<16384, 256, 0, stream>>>(x, pHi, pLo);
    prep_w<<<dim3(128, 32), 256, 0, stream>>>(theta_w, f_w, wHi, wLo);
    prep_g<<<dim3(128, 128), 256, 0, stream>>>(g_w, gwt);
    gemm1<<<dim3(32, 8), 256, 0, stream>>>(pHi, pLo, wHi, wLo, theta_b, f_b, C1);
    scores_softmax<<<dim3(16, 16), 256, 0, stream>>>(C1, wts);
    gemm2<<<dim3(32, 32), 256, 0, stream>>>(pHi, gwt, g_b, wts, x, scale, (float*)d_out);
}

// Round 3
// 571.938 us; speedup vs baseline: 1.4864x; 1.4864x over previous
//
#include <hip/hip_runtime.h>
#include <hip/hip_bf16.h>
#include <stdint.h>

// LocalEnhancementModule on MI355X (gfx950).
// B=16 C=16 H=W=256 NP=16 -> P=256, D=4096, E=512, M=B*P=4096.
//  prep_p: x -> p_hi/p_lo bf16 [M,D]
//  prep_w: [theta_w|f_w] -> transposed bf16 hi/lo [1024,D]
//  gemm1 : 3-pass split bf16 MFMA, split-K x2 (512 blocks = 2/CU) -> C1a/C1b fp32
//  combine: C1a+C1b+bias -> thf hi/lo bf16 [4096,1024]
//  scores: 3-pass hi/lo bf16 MFMA batched GEMM theta@f^T -> S fp32 [16,256,256]
//  softmax_rows: in-place row softmax on S
//  prep_g: g_w -> transposed bf16 [D,D] (runs late; reuses pLo's space)
//  gemm2 : bf16 MFMA p_hi @ g_w^T, epilogue out = scale*w*(acc+g_b) + x
//
// Workspace (lifetime-packed, max 128 MiB):
//  pHi [0,32) | pLo→gwt [32,64) | wHi [64,72) | wLo [72,80)
//  C1a→S [80,96) | C1b [96,112) | thfHi [112,120) | thfLo [120,128)

typedef __hip_bfloat16 bf16;
typedef __bf16 bf16x8 __attribute__((ext_vector_type(8)));
typedef float f32x4 __attribute__((ext_vector_type(4)));

#define GLOBAL_AS __attribute__((address_space(1)))
#define LDS_AS __attribute__((address_space(3)))

__device__ __forceinline__ void gload_lds16(const void* g, void* l) {
    void* gg = const_cast<void*>(g);
    __builtin_amdgcn_global_load_lds((GLOBAL_AS void*)gg, (LDS_AS void*)l, 16, 0, 0);
}

// ---------------- prep kernels ----------------

__global__ __launch_bounds__(256) void prep_p(const float* __restrict__ x,
                                              bf16* __restrict__ pHi,
                                              bf16* __restrict__ pLo) {
    int tid = blockIdx.x * 256 + threadIdx.x;        // over [B][C][H][W/4]
    int w4 = tid & 63;
    int h  = (tid >> 6) & 255;
    int c  = (tid >> 14) & 15;
    int b  = tid >> 18;
    float4 v = ((const float4*)x)[tid];
    int i = h >> 4, y = h & 15, j = w4 >> 2, zb = (w4 & 3) * 4;
    int m = b * 256 + i * 16 + j;
    int k = c * 256 + y * 16 + zb;
    size_t o = (size_t)m * 4096 + k;
    float vs[4] = {v.x, v.y, v.z, v.w};
#pragma unroll
    for (int q = 0; q < 4; ++q) {
        bf16 hv = __float2bfloat16(vs[q]);
        float rem = vs[q] - __bfloat162float(hv);
        pHi[o + q] = hv;
        pLo[o + q] = __float2bfloat16(rem);
    }
}

__global__ __launch_bounds__(256) void prep_w(const float* __restrict__ theta_w,
                                              const float* __restrict__ f_w,
                                              bf16* __restrict__ wHi,
                                              bf16* __restrict__ wLo) {
    __shared__ float tile[32][33];
    int t = threadIdx.x;
    int tx = t & 31, ty = t >> 5;
    int k0 = blockIdx.x * 32;
    int e0 = blockIdx.y * 32;
#pragma unroll
    for (int r = 0; r < 4; ++r) {
        int k = k0 + ty + r * 8;
        int e = e0 + tx;
        float v = (e < 512) ? theta_w[(size_t)k * 512 + e]
                            : f_w[(size_t)k * 512 + (e - 512)];
        tile[ty + r * 8][tx] = v;
    }
    __syncthreads();
#pragma unroll
    for (int r = 0; r < 4; ++r) {
        int e = e0 + ty + r * 8;
        int k = k0 + tx;
        float v = tile[tx][ty + r * 8];
        bf16 hv = __float2bfloat16(v);
        float rem = v - __bfloat162float(hv);
        wHi[(size_t)e * 4096 + k] = hv;
        wLo[(size_t)e * 4096 + k] = __float2bfloat16(rem);
    }
}

__global__ __launch_bounds__(256) void prep_g(const float* __restrict__ g_w,
                                              bf16* __restrict__ gwt) {
    __shared__ float tile[32][33];
    int t = threadIdx.x;
    int tx = t & 31, ty = t >> 5;
    int k0 = blockIdx.x * 32;
    int n0 = blockIdx.y * 32;
#pragma unroll
    for (int r = 0; r < 4; ++r) {
        int k = k0 + ty + r * 8;
        tile[ty + r * 8][tx] = g_w[(size_t)k * 4096 + (n0 + tx)];
    }
    __syncthreads();
#pragma unroll
    for (int r = 0; r < 4; ++r) {
        int n = n0 + ty + r * 8;
        int k = k0 + tx;
        gwt[(size_t)n * 4096 + k] = __float2bfloat16(tile[tx][ty + r * 8]);
    }
}

// ---------------- shared GEMM core ----------------
// BM=BN=128, BK=32, 256 threads (4 waves, 2x2 wave grid, 64x64/wave).
__device__ __forceinline__ void gemm_pass(const bf16* A, const bf16* Bt,
                                          int lda, int ldb, int m0, int n0,
                                          int kbase, int ksteps,
                                          bf16* As, bf16* Bs, f32x4 (&acc)[4][4]) {
    int t = threadIdx.x, lane = t & 63, wave = t >> 6;
    int wm = wave & 1, wn = wave >> 1;
    int lr = lane & 15, lq = lane >> 4;
    const bf16* gA = A + (size_t)m0 * lda;
    const bf16* gB = Bt + (size_t)n0 * ldb;
    int chunk0 = wave * 2;
    int srow0 = lane >> 2;
    int cb = (lane & 3) * 16;   // byte offset within a 64B row
    for (int ks = 0; ks < ksteps; ++ks) {
        int kt = kbase + ks * 32;
#pragma unroll
        for (int tt = 0; tt < 2; ++tt) {
            int chunk = chunk0 + tt;
            int row = chunk * 16 + srow0;
            gload_lds16((const char*)(gA + ((size_t)row * lda + kt)) + cb,
                        (char*)As + chunk * 1024);
            gload_lds16((const char*)(gB + ((size_t)row * ldb + kt)) + cb,
                        (char*)Bs + chunk * 1024);
        }
        __syncthreads();
        bf16x8 af[4], bfr[4];
#pragma unroll
        for (int mt = 0; mt < 4; ++mt)
            af[mt] = *(const bf16x8*)((const char*)As + (wm * 64 + mt * 16 + lr) * 64 + lq * 16);
#pragma unroll
        for (int nt = 0; nt < 4; ++nt)
            bfr[nt] = *(const bf16x8*)((const char*)Bs + (wn * 64 + nt * 16 + lr) * 64 + lq * 16);
#pragma unroll
        for (int mt = 0; mt < 4; ++mt)
#pragma unroll
            for (int nt = 0; nt < 4; ++nt)
                acc[mt][nt] = __builtin_amdgcn_mfma_f32_16x16x32_bf16(
                    af[mt], bfr[nt], acc[mt][nt], 0, 0, 0);
        __syncthreads();
    }
}

// ---------------- gemm1: theta/f hi/lo split, split-K x2 ----------------

__global__ __launch_bounds__(256) void gemm1(const bf16* __restrict__ pHi,
                                             const bf16* __restrict__ pLo,
                                             const bf16* __restrict__ wHi,
                                             const bf16* __restrict__ wLo,
                                             float* __restrict__ C1a,
                                             float* __restrict__ C1b) {
    __shared__ bf16 As[128 * 32];
    __shared__ bf16 Bs[128 * 32];
    int m0 = blockIdx.x * 128, n0 = blockIdx.y * 128;
    int kbase = blockIdx.z * 2048;
    f32x4 acc[4][4] = {};
    gemm_pass(pLo, wHi, 4096, 4096, m0, n0, kbase, 64, As, Bs, acc);   // lo*hi
    gemm_pass(pHi, wLo, 4096, 4096, m0, n0, kbase, 64, As, Bs, acc);   // hi*lo
    gemm_pass(pHi, wHi, 4096, 4096, m0, n0, kbase, 64, As, Bs, acc);   // hi*hi
    float* C = blockIdx.z ? C1b : C1a;
    int t = threadIdx.x, lane = t & 63, wave = t >> 6;
    int wm = wave & 1, wn = wave >> 1;
    int lr = lane & 15, lq = lane >> 4;
#pragma unroll
    for (int mt = 0; mt < 4; ++mt)
#pragma unroll
        for (int nt = 0; nt < 4; ++nt) {
            int col = n0 + wn * 64 + nt * 16 + lr;
#pragma unroll
            for (int reg = 0; reg < 4; ++reg) {
                int row = m0 + wm * 64 + mt * 16 + lq * 4 + reg;
                C[(size_t)row * 1024 + col] = acc[mt][nt][reg];
            }
        }
}

// ---------------- combine: partial sums + bias -> bf16 hi/lo ----------------

__global__ __launch_bounds__(256) void combine(const float* __restrict__ C1a,
                                               const float* __restrict__ C1b,
                                               const float* __restrict__ theta_b,
                                               const float* __restrict__ f_b,
                                               bf16* __restrict__ thfHi,
                                               bf16* __restrict__ thfLo) {
    int id = blockIdx.x * 256 + threadIdx.x;    // float4 index over [4096,256]
    int c4 = id & 255;
    float4 va = ((const float4*)C1a)[id];
    float4 vb = ((const float4*)C1b)[id];
    float vs[4] = {va.x + vb.x, va.y + vb.y, va.z + vb.z, va.w + vb.w};
    union { ushort4 u; unsigned short s[4]; } H, L;
#pragma unroll
    for (int q = 0; q < 4; ++q) {
        int col = c4 * 4 + q;
        float bias = (col < 512) ? theta_b[col] : f_b[col - 512];
        float v = vs[q] + bias;
        bf16 h = __float2bfloat16(v);
        float rem = v - __bfloat162float(h);
        bf16 l = __float2bfloat16(rem);
        H.s[q] = *(unsigned short*)&h;
        L.s[q] = *(unsigned short*)&l;
    }
    ((ushort4*)thfHi)[id] = H.u;
    ((ushort4*)thfLo)[id] = L.u;
}

// ---------------- scores: batched theta @ f^T via MFMA (hi/lo 3-pass) ----------------

__global__ __launch_bounds__(256) void scores(const bf16* __restrict__ thfHi,
                                              const bf16* __restrict__ thfLo,
                                              float* __restrict__ S) {
    __shared__ bf16 As[128 * 32];
    __shared__ bf16 Bs[128 * 32];
    int m0 = blockIdx.x * 128, n0 = blockIdx.y * 128, b = blockIdx.z;
    const bf16* Ahi = thfHi + (size_t)b * 256 * 1024;
    const bf16* Alo = thfLo + (size_t)b * 256 * 1024;
    f32x4 acc[4][4] = {};
    gemm_pass(Ahi, Ahi + 512, 1024, 1024, m0, n0, 0, 16, As, Bs, acc);  // hi*hi
    gemm_pass(Alo, Ahi + 512, 1024, 1024, m0, n0, 0, 16, As, Bs, acc);  // lo*hi
    gemm_pass(Ahi, Alo + 512, 1024, 1024, m0, n0, 0, 16, As, Bs, acc);  // hi*lo
    float* Sb = S + (size_t)b * 65536;
    int t = threadIdx.x, lane = t & 63, wave = t >> 6;
    int wm = wave & 1, wn = wave >> 1;
    int lr = lane & 15, lq = lane >> 4;
#pragma unroll
    for (int mt = 0; mt < 4; ++mt)
#pragma unroll
        for (int nt = 0; nt < 4; ++nt) {
            int col = n0 + wn * 64 + nt * 16 + lr;
#pragma unroll
            for (int reg = 0; reg < 4; ++reg) {
                int row = m0 + wm * 64 + mt * 16 + lq * 4 + reg;
                Sb[(size_t)row * 256 + col] = acc[mt][nt][reg];
            }
        }
}

// ---------------- softmax: one wave per 256-wide row, in place ----------------

__global__ __launch_bounds__(256) void softmax_rows(float* __restrict__ S) {
    int row = blockIdx.x * 4 + (threadIdx.x >> 6);
    int lane = threadIdx.x & 63;
    float4* p = (float4*)(S + (size_t)row * 256);
    float4 v = p[lane];
    float mx = fmaxf(fmaxf(v.x, v.y), fmaxf(v.z, v.w));
#pragma unroll
    for (int s = 32; s >= 1; s >>= 1) mx = fmaxf(mx, __shfl_xor(mx, s, 64));
    v.x = expf(v.x - mx); v.y = expf(v.y - mx);
    v.z = expf(v.z - mx); v.w = expf(v.w - mx);
    float sm = (v.x + v.y) + (v.z + v.w);
#pragma unroll
    for (int s = 32; s >= 1; s >>= 1) sm += __shfl_xor(sm, s, 64);
    float inv = 1.0f / sm;
    v.x *= inv; v.y *= inv; v.z *= inv; v.w *= inv;
    p[lane] = v;
}

// ---------------- gemm2: g GEMM + fused gating epilogue ----------------

__global__ __launch_bounds__(256) void gemm2(const bf16* __restrict__ pHi,
                                             const bf16* __restrict__ gwt,
                                             const float* __restrict__ g_b,
                                             const float* __restrict__ wts,
                                             const float* __restrict__ x,
                                             const float* __restrict__ scale,
                                             float* __restrict__ out) {
    __shared__ bf16 As[128 * 32];
    __shared__ bf16 Bs[128 * 32];
    int m0 = blockIdx.x * 128, n0 = blockIdx.y * 128;
    f32x4 acc[4][4] = {};
    gemm_pass(pHi, gwt, 4096, 4096, m0, n0, 0, 128, As, Bs, acc);
    int t = threadIdx.x, lane = t & 63, wave = t >> 6;
    int wm = wave & 1, wn = wave >> 1;
    int lr = lane & 15, lq = lane >> 4;
    float scl = scale[0];
#pragma unroll
    for (int mt = 0; mt < 4; ++mt)
#pragma unroll
        for (int nt = 0; nt < 4; ++nt) {
            int ng = n0 + wn * 64 + nt * 16 + lr;   // d_out = cc*256 + nidx
            float gb = g_b[ng];
            int cc = ng >> 8, nidx = ng & 255;
            int y = nidx >> 4, z = nidx & 15;
#pragma unroll
            for (int reg = 0; reg < 4; ++reg) {
                int mg = m0 + wm * 64 + mt * 16 + lq * 4 + reg;  // b*256 + pi
                int bb = mg >> 8, pi = mg & 255;
                int i = pi >> 4, j = pi & 15;
                float wt = wts[(size_t)mg * 256 + nidx];
                float gval = acc[mt][nt][reg] + gb;
                size_t idx = ((((size_t)(bb * 16 + cc)) * 256) + i * 16 + y) * 256
                             + (j * 16 + z);
                out[idx] = scl * wt * gval + x[idx];
            }
        }
}

// ---------------- launch ----------------

extern "C" void kernel_launch(void* const* d_in, const int* in_sizes, int n_in,
                              void* d_out, int out_size, void* d_ws, size_t ws_size,
                              hipStream_t stream) {
    const float* x       = (const float*)d_in[0];
    const float* theta_w = (const float*)d_in[1];
    const float* theta_b = (const float*)d_in[2];
    const float* f_w     = (const float*)d_in[3];
    const float* f_b     = (const float*)d_in[4];
    const float* g_w     = (const float*)d_in[5];
    const float* g_b     = (const float*)d_in[6];
    const float* scale   = (const float*)d_in[7];
    (void)in_sizes; (void)n_in; (void)out_size; (void)ws_size;

    const size_t MiB = 1048576;
    char* ws = (char*)d_ws;
    bf16*  pHi   = (bf16*)(ws);                     // [0,32) live whole run
    bf16*  pLo   = (bf16*)(ws + 32 * MiB);          // [32,64) dead after gemm1
    bf16*  gwt   = (bf16*)(ws + 32 * MiB);          //   reuse after gemm1
    bf16*  wHi   = (bf16*)(ws + 64 * MiB);          // [64,72) dead after gemm1
    bf16*  wLo   = (bf16*)(ws + 72 * MiB);          // [72,80) dead after gemm1
    float* C1a   = (float*)(ws + 80 * MiB);         // [80,96) dead after combine
    float* S     = (float*)(ws + 80 * MiB);         //   reuse: [80,84)
    float* C1b   = (float*)(ws + 96 * MiB);         // [96,112) dead after combine
    bf16*  thfHi = (bf16*)(ws + 112 * MiB);         // [112,120) dead after scores
    bf16*  thfLo = (bf16*)(ws + 120 * MiB);         // [120,128) dead after scores

    prep_p<<<16384, 256, 0, stream>>>(x, pHi, pLo);
    prep_w<<<dim3(128, 32), 256, 0, stream>>>(theta_w, f_w, wHi, wLo);
    gemm1<<<dim3(32, 8, 2), 256, 0, stream>>>(pHi, pLo, wHi, wLo, C1a, C1b);
    combine<<<4096, 256, 0, stream>>>(C1a, C1b, theta_b, f_b, thfHi, thfLo);
    scores<<<dim3(2, 2, 16), 256, 0, stream>>>(thfHi, thfLo, S);
    softmax_rows<<<1024, 256, 0, stream>>>(S);
    prep_g<<<dim3(128, 128), 256, 0, stream>>>(g_w, gwt);   // overwrites pLo (dead)
    gemm2<<<dim3(32, 32), 256, 0, stream>>>(pHi, gwt, g_b, S, x, scale, (float*)d_out);
}

// Round 4
// 542.925 us; speedup vs baseline: 1.5658x; 1.0534x over previous
//
#include <hip/hip_runtime.h>
#include <hip/hip_bf16.h>
#include <stdint.h>

// LocalEnhancementModule on MI355X (gfx950).
// B=16 C=16 H=W=256 NP=16 -> P=256, D=4096, E=512, M=B*P=4096.
//  prep_pw : x -> p_hi/p_lo bf16 [M,D]  +  [theta_w|f_w] -> w hi/lo [1024,D]
//  gemm1f  : fused 3-product hi/lo bf16 MFMA, split-K x2 -> C1a/C1b fp32 [M,1024]
//            (operand-swapped: A=w rows, B=p rows -> float4 C-stores)
//  combine_prepg : C1a+C1b+bias -> thf hi/lo bf16 [M,1024]; also g_w -> gwt bf16 [D,D]
//  scores  : 3-pass hi/lo MFMA theta@f^T -> S fp32 [16,256,256] (swapped, float4 stores)
//  softmax_rows : in-place row softmax on S
//  gemm2   : bf16 MFMA, A=gwt rows, B=pHi rows; float4 epilogue
//            out = scale*w*(acc+g_b) + x
//
// Workspace (lifetime-packed, max 128 MiB):
//  pHi [0,32) | pLo->gwt [32,64) | wHi [64,72) | wLo [72,80)
//  C1a->S [80,96) | C1b [96,112) | thfHi [112,120) | thfLo [120,128)

typedef __hip_bfloat16 bf16;
typedef __bf16 bf16x8 __attribute__((ext_vector_type(8)));
typedef float f32x4 __attribute__((ext_vector_type(4)));

#define GLOBAL_AS __attribute__((address_space(1)))
#define LDS_AS __attribute__((address_space(3)))

__device__ __forceinline__ void gload_lds16(const void* g, void* l) {
    void* gg = const_cast<void*>(g);
    __builtin_amdgcn_global_load_lds((GLOBAL_AS void*)gg, (LDS_AS void*)l, 16, 0, 0);
}

// ---------------- merged prep: p (hi/lo) + w (hi/lo transposed) ----------------

__global__ __launch_bounds__(256) void prep_pw(const float* __restrict__ x,
                                               const float* __restrict__ theta_w,
                                               const float* __restrict__ f_w,
                                               bf16* __restrict__ pHi,
                                               bf16* __restrict__ pLo,
                                               bf16* __restrict__ wHi,
                                               bf16* __restrict__ wLo) {
    __shared__ float tile[32][33];
    int blk = blockIdx.x;
    if (blk < 16384) {
        int tid = blk * 256 + threadIdx.x;           // over [B][C][H][W/4]
        int w4 = tid & 63;
        int h  = (tid >> 6) & 255;
        int c  = (tid >> 14) & 15;
        int b  = tid >> 18;
        float4 v = ((const float4*)x)[tid];
        int i = h >> 4, y = h & 15, j = w4 >> 2, zb = (w4 & 3) * 4;
        int m = b * 256 + i * 16 + j;
        int k = c * 256 + y * 16 + zb;
        size_t o = (size_t)m * 4096 + k;
        float vs[4] = {v.x, v.y, v.z, v.w};
#pragma unroll
        for (int q = 0; q < 4; ++q) {
            bf16 hv = __float2bfloat16(vs[q]);
            float rem = vs[q] - __bfloat162float(hv);
            pHi[o + q] = hv;
            pLo[o + q] = __float2bfloat16(rem);
        }
    } else {
        int bid = blk - 16384;                       // 4096 blocks: (k/32)=bid&127, (e/32)=bid>>7
        int t = threadIdx.x;
        int tx = t & 31, ty = t >> 5;
        int k0 = (bid & 127) * 32;
        int e0 = (bid >> 7) * 32;
#pragma unroll
        for (int r = 0; r < 4; ++r) {
            int k = k0 + ty + r * 8;
            int e = e0 + tx;
            float v = (e < 512) ? theta_w[(size_t)k * 512 + e]
                                : f_w[(size_t)k * 512 + (e - 512)];
            tile[ty + r * 8][tx] = v;
        }
        __syncthreads();
#pragma unroll
        for (int r = 0; r < 4; ++r) {
            int e = e0 + ty + r * 8;
            int k = k0 + tx;
            float v = tile[tx][ty + r * 8];
            bf16 hv = __float2bfloat16(v);
            float rem = v - __bfloat162float(hv);
            wHi[(size_t)e * 4096 + k] = hv;
            wLo[(size_t)e * 4096 + k] = __float2bfloat16(rem);
        }
    }
}

// ---------------- generic GEMM pass (scores / gemm2) ----------------
// BM=BN=128, BK=32, 256 threads (4 waves, 2x2 wave grid, 64x64/wave).
// First operand tile from A (rows -> output "row"/reg dim),
// second from Bt (rows -> output "col"/lane dim).
__device__ __forceinline__ void gemm_pass(const bf16* A, const bf16* Bt,
                                          int lda, int ldb, int m0, int n0,
                                          int kbase, int ksteps,
                                          bf16* As, bf16* Bs, f32x4 (&acc)[4][4]) {
    int t = threadIdx.x, lane = t & 63, wave = t >> 6;
    int wm = wave & 1, wn = wave >> 1;
    int lr = lane & 15, lq = lane >> 4;
    const bf16* gA = A + (size_t)m0 * lda;
    const bf16* gB = Bt + (size_t)n0 * ldb;
    int chunk0 = wave * 2;
    int srow0 = lane >> 2;
    int cb = (lane & 3) * 16;
    for (int ks = 0; ks < ksteps; ++ks) {
        int kt = kbase + ks * 32;
#pragma unroll
        for (int tt = 0; tt < 2; ++tt) {
            int chunk = chunk0 + tt;
            int row = chunk * 16 + srow0;
            gload_lds16((const char*)(gA + ((size_t)row * lda + kt)) + cb,
                        (char*)As + chunk * 1024);
            gload_lds16((const char*)(gB + ((size_t)row * ldb + kt)) + cb,
                        (char*)Bs + chunk * 1024);
        }
        __syncthreads();
        bf16x8 af[4], bfr[4];
#pragma unroll
        for (int mt = 0; mt < 4; ++mt)
            af[mt] = *(const bf16x8*)((const char*)As + (wm * 64 + mt * 16 + lr) * 64 + lq * 16);
#pragma unroll
        for (int nt = 0; nt < 4; ++nt)
            bfr[nt] = *(const bf16x8*)((const char*)Bs + (wn * 64 + nt * 16 + lr) * 64 + lq * 16);
#pragma unroll
        for (int mt = 0; mt < 4; ++mt)
#pragma unroll
            for (int nt = 0; nt < 4; ++nt)
                acc[mt][nt] = __builtin_amdgcn_mfma_f32_16x16x32_bf16(
                    af[mt], bfr[nt], acc[mt][nt], 0, 0, 0);
        __syncthreads();
    }
}

// ---------------- gemm1f: fused 3-product hi/lo, split-K x2, swapped ----------------
// A = w rows (e-dim, 1024), B = p rows (patch dim, 4096).

__global__ __launch_bounds__(256) void gemm1f(const bf16* __restrict__ pHi,
                                              const bf16* __restrict__ pLo,
                                              const bf16* __restrict__ wHi,
                                              const bf16* __restrict__ wLo,
                                              float* __restrict__ C1a,
                                              float* __restrict__ C1b) {
    __shared__ bf16 AsHi[128 * 32];
    __shared__ bf16 AsLo[128 * 32];
    __shared__ bf16 BsHi[128 * 32];
    __shared__ bf16 BsLo[128 * 32];
    int m0 = blockIdx.x * 128;      // e-dim
    int n0 = blockIdx.y * 128;      // patch dim
    int kbase = blockIdx.z * 2048;
    int t = threadIdx.x, lane = t & 63, wave = t >> 6;
    int wm = wave & 1, wn = wave >> 1;
    int lr = lane & 15, lq = lane >> 4;
    const bf16* gAh = wHi + (size_t)m0 * 4096;
    const bf16* gAl = wLo + (size_t)m0 * 4096;
    const bf16* gBh = pHi + (size_t)n0 * 4096;
    const bf16* gBl = pLo + (size_t)n0 * 4096;
    int chunk0 = wave * 2;
    int srow0 = lane >> 2;
    int cb = (lane & 3) * 16;
    f32x4 acc[4][4] = {};
    for (int ks = 0; ks < 64; ++ks) {
        int kt = kbase + ks * 32;
#pragma unroll
        for (int tt = 0; tt < 2; ++tt) {
            int chunk = chunk0 + tt;
            size_t off = (size_t)(chunk * 16 + srow0) * 4096 + kt;
            gload_lds16((const char*)(gAh + off) + cb, (char*)AsHi + chunk * 1024);
            gload_lds16((const char*)(gAl + off) + cb, (char*)AsLo + chunk * 1024);
            gload_lds16((const char*)(gBh + off) + cb, (char*)BsHi + chunk * 1024);
            gload_lds16((const char*)(gBl + off) + cb, (char*)BsLo + chunk * 1024);
        }
        __syncthreads();
        bf16x8 ah[4], al[4], bh[4], bl[4];
#pragma unroll
        for (int mt = 0; mt < 4; ++mt) {
            int ro = (wm * 64 + mt * 16 + lr) * 64 + lq * 16;
            ah[mt] = *(const bf16x8*)((const char*)AsHi + ro);
            al[mt] = *(const bf16x8*)((const char*)AsLo + ro);
        }
#pragma unroll
        for (int nt = 0; nt < 4; ++nt) {
            int ro = (wn * 64 + nt * 16 + lr) * 64 + lq * 16;
            bh[nt] = *(const bf16x8*)((const char*)BsHi + ro);
            bl[nt] = *(const bf16x8*)((const char*)BsLo + ro);
        }
#pragma unroll
        for (int mt = 0; mt < 4; ++mt)
#pragma unroll
            for (int nt = 0; nt < 4; ++nt)
                acc[mt][nt] = __builtin_amdgcn_mfma_f32_16x16x32_bf16(
                    ah[mt], bl[nt], acc[mt][nt], 0, 0, 0);
#pragma unroll
        for (int mt = 0; mt < 4; ++mt)
#pragma unroll
            for (int nt = 0; nt < 4; ++nt)
                acc[mt][nt] = __builtin_amdgcn_mfma_f32_16x16x32_bf16(
                    al[mt], bh[nt], acc[mt][nt], 0, 0, 0);
#pragma unroll
        for (int mt = 0; mt < 4; ++mt)
#pragma unroll
            for (int nt = 0; nt < 4; ++nt)
                acc[mt][nt] = __builtin_amdgcn_mfma_f32_16x16x32_bf16(
                    ah[mt], bh[nt], acc[mt][nt], 0, 0, 0);
        __syncthreads();
    }
    float* C = blockIdx.z ? C1b : C1a;
#pragma unroll
    for (int mt = 0; mt < 4; ++mt) {
        int e = m0 + wm * 64 + mt * 16 + lq * 4;       // +reg, 4-consecutive
#pragma unroll
        for (int nt = 0; nt < 4; ++nt) {
            int p = n0 + wn * 64 + nt * 16 + lr;
            *(float4*)(C + (size_t)p * 1024 + e) = *(float4*)&acc[mt][nt];
        }
    }
}

// ---------------- combine + prep_g merged ----------------

__global__ __launch_bounds__(256) void combine_prepg(const float* __restrict__ C1a,
                                                     const float* __restrict__ C1b,
                                                     const float* __restrict__ theta_b,
                                                     const float* __restrict__ f_b,
                                                     const float* __restrict__ g_w,
                                                     bf16* __restrict__ thfHi,
                                                     bf16* __restrict__ thfLo,
                                                     bf16* __restrict__ gwt) {
    __shared__ float tile[32][33];
    int blk = blockIdx.x;
    if (blk < 4096) {
        int id = blk * 256 + threadIdx.x;    // float4 index over [4096,256]
        int c4 = id & 255;
        float4 va = ((const float4*)C1a)[id];
        float4 vb = ((const float4*)C1b)[id];
        float vs[4] = {va.x + vb.x, va.y + vb.y, va.z + vb.z, va.w + vb.w};
        union { ushort4 u; unsigned short s[4]; } H, L;
#pragma unroll
        for (int q = 0; q < 4; ++q) {
            int col = c4 * 4 + q;
            float bias = (col < 512) ? theta_b[col] : f_b[col - 512];
            float v = vs[q] + bias;
            bf16 h = __float2bfloat16(v);
            float rem = v - __bfloat162float(h);
            bf16 l = __float2bfloat16(rem);
            H.s[q] = *(unsigned short*)&h;
            L.s[q] = *(unsigned short*)&l;
        }
        ((ushort4*)thfHi)[id] = H.u;
        ((ushort4*)thfLo)[id] = L.u;
    } else {
        int bid = blk - 4096;               // 16384 blocks
        int t = threadIdx.x;
        int tx = t & 31, ty = t >> 5;
        int k0 = (bid & 127) * 32;
        int n0 = (bid >> 7) * 32;
#pragma unroll
        for (int r = 0; r < 4; ++r) {
            int k = k0 + ty + r * 8;
            tile[ty + r * 8][tx] = g_w[(size_t)k * 4096 + (n0 + tx)];
        }
        __syncthreads();
#pragma unroll
        for (int r = 0; r < 4; ++r) {
            int n = n0 + ty + r * 8;
            int k = k0 + tx;
            gwt[(size_t)n * 4096 + k] = __float2bfloat16(tile[tx][ty + r * 8]);
        }
    }
}

// ---------------- scores: f/theta swapped MFMA, float4 stores ----------------

__global__ __launch_bounds__(256) void scores(const bf16* __restrict__ thfHi,
                                              const bf16* __restrict__ thfLo,
                                              float* __restrict__ S) {
    __shared__ bf16 As[128 * 32];
    __shared__ bf16 Bs[128 * 32];
    int m0 = blockIdx.x * 128;     // q (f index)
    int n0 = blockIdx.y * 128;     // p (theta index)
    int b = blockIdx.z;
    const bf16* Ahi = thfHi + (size_t)b * 256 * 1024;
    const bf16* Alo = thfLo + (size_t)b * 256 * 1024;
    f32x4 acc[4][4] = {};
    gemm_pass(Ahi + 512, Ahi, 1024, 1024, m0, n0, 0, 16, As, Bs, acc);  // f_hi * th_hi
    gemm_pass(Ahi + 512, Alo, 1024, 1024, m0, n0, 0, 16, As, Bs, acc);  // f_hi * th_lo
    gemm_pass(Alo + 512, Ahi, 1024, 1024, m0, n0, 0, 16, As, Bs, acc);  // f_lo * th_hi
    float* Sb = S + (size_t)b * 65536;
    int t = threadIdx.x, lane = t & 63, wave = t >> 6;
    int wm = wave & 1, wn = wave >> 1;
    int lr = lane & 15, lq = lane >> 4;
#pragma unroll
    for (int mt = 0; mt < 4; ++mt) {
        int q = m0 + wm * 64 + mt * 16 + lq * 4;
#pragma unroll
        for (int nt = 0; nt < 4; ++nt) {
            int p = n0 + wn * 64 + nt * 16 + lr;
            *(float4*)(Sb + (size_t)p * 256 + q) = *(float4*)&acc[mt][nt];
        }
    }
}

// ---------------- softmax: one wave per 256-wide row, in place ----------------

__global__ __launch_bounds__(256) void softmax_rows(float* __restrict__ S) {
    int row = blockIdx.x * 4 + (threadIdx.x >> 6);
    int lane = threadIdx.x & 63;
    float4* p = (float4*)(S + (size_t)row * 256);
    float4 v = p[lane];
    float mx = fmaxf(fmaxf(v.x, v.y), fmaxf(v.z, v.w));
#pragma unroll
    for (int s = 32; s >= 1; s >>= 1) mx = fmaxf(mx, __shfl_xor(mx, s, 64));
    v.x = expf(v.x - mx); v.y = expf(v.y - mx);
    v.z = expf(v.z - mx); v.w = expf(v.w - mx);
    float sm = (v.x + v.y) + (v.z + v.w);
#pragma unroll
    for (int s = 32; s >= 1; s >>= 1) sm += __shfl_xor(sm, s, 64);
    float inv = 1.0f / sm;
    v.x *= inv; v.y *= inv; v.z *= inv; v.w *= inv;
    p[lane] = v;
}

// ---------------- gemm2: swapped operands + float4 epilogue ----------------
// A = gwt rows (g-output dim n, 4096), B = pHi rows (patch dim m, 4096).

__global__ __launch_bounds__(256) void gemm2(const bf16* __restrict__ pHi,
                                             const bf16* __restrict__ gwt,
                                             const float* __restrict__ g_b,
                                             const float* __restrict__ wts,
                                             const float* __restrict__ x,
                                             const float* __restrict__ scale,
                                             float* __restrict__ out) {
    __shared__ bf16 As[128 * 32];
    __shared__ bf16 Bs[128 * 32];
    int m0 = blockIdx.x * 128;    // g-output dim
    int n0 = blockIdx.y * 128;    // patch dim
    f32x4 acc[4][4] = {};
    gemm_pass(gwt, pHi, 4096, 4096, m0, n0, 0, 128, As, Bs, acc);
    int t = threadIdx.x, lane = t & 63, wave = t >> 6;
    int wm = wave & 1, wn = wave >> 1;
    int lr = lane & 15, lq = lane >> 4;
    float scl = scale[0];
#pragma unroll
    for (int mt = 0; mt < 4; ++mt) {
        int ng = m0 + wm * 64 + mt * 16 + lq * 4;      // +reg, 4-consecutive
        int cc = ng >> 8;
        int y = (ng >> 4) & 15;
        int zq = ng & 255;                              // y*16 + z0 (mult of 4)
        float4 gb4 = *(const float4*)(g_b + ng);
#pragma unroll
        for (int nt = 0; nt < 4; ++nt) {
            int mg = n0 + wn * 64 + nt * 16 + lr;       // b*256 + pi
            int bb = mg >> 8, pi = mg & 255;
            int i = pi >> 4, j = pi & 15;
            float4 wt4 = *(const float4*)(wts + (size_t)mg * 256 + zq);
            size_t idx = ((((size_t)(bb * 16 + cc)) * 256) + i * 16 + y) * 256
                         + j * 16 + (ng & 15);
            float4 xv = *(const float4*)(x + idx);
            f32x4 a = acc[mt][nt];
            float4 o;
            o.x = scl * wt4.x * (a[0] + gb4.x) + xv.x;
            o.y = scl * wt4.y * (a[1] + gb4.y) + xv.y;
            o.z = scl * wt4.z * (a[2] + gb4.z) + xv.z;
            o.w = scl * wt4.w * (a[3] + gb4.w) + xv.w;
            *(float4*)(out + idx) = o;
        }
    }
}

// ---------------- launch ----------------

extern "C" void kernel_launch(void* const* d_in, const int* in_sizes, int n_in,
                              void* d_out, int out_size, void* d_ws, size_t ws_size,
                              hipStream_t stream) {
    const float* x       = (const float*)d_in[0];
    const float* theta_w = (const float*)d_in[1];
    const float* theta_b = (const float*)d_in[2];
    const float* f_w     = (const float*)d_in[3];
    const float* f_b     = (const float*)d_in[4];
    const float* g_w     = (const float*)d_in[5];
    const float* g_b     = (const float*)d_in[6];
    const float* scale   = (const float*)d_in[7];
    (void)in_sizes; (void)n_in; (void)out_size; (void)ws_size;

    const size_t MiB = 1048576;
    char* ws = (char*)d_ws;
    bf16*  pHi   = (bf16*)(ws);                     // [0,32) live whole run
    bf16*  pLo   = (bf16*)(ws + 32 * MiB);          // [32,64) dead after gemm1f
    bf16*  gwt   = (bf16*)(ws + 32 * MiB);          //   reuse after gemm1f
    bf16*  wHi   = (bf16*)(ws + 64 * MiB);          // [64,72) dead after gemm1f
    bf16*  wLo   = (bf16*)(ws + 72 * MiB);          // [72,80) dead after gemm1f
    float* C1a   = (float*)(ws + 80 * MiB);         // [80,96) dead after combine
    float* S     = (float*)(ws + 80 * MiB);         //   reuse: [80,84)
    float* C1b   = (float*)(ws + 96 * MiB);         // [96,112) dead after combine
    bf16*  thfHi = (bf16*)(ws + 112 * MiB);         // [112,120) dead after scores
    bf16*  thfLo = (bf16*)(ws + 120 * MiB);         // [120,128) dead after scores

    prep_pw<<<20480, 256, 0, stream>>>(x, theta_w, f_w, pHi, pLo, wHi, wLo);
    gemm1f<<<dim3(8, 32, 2), 256, 0, stream>>>(pHi, pLo, wHi, wLo, C1a, C1b);
    combine_prepg<<<20480, 256, 0, stream>>>(C1a, C1b, theta_b, f_b, g_w,
                                             thfHi, thfLo, gwt);
    scores<<<dim3(2, 2, 16), 256, 0, stream>>>(thfHi, thfLo, S);
    softmax_rows<<<1024, 256, 0, stream>>>(S);
    gemm2<<<dim3(32, 32), 256, 0, stream>>>(pHi, gwt, g_b, S, x, scale, (float*)d_out);
}